// Round 5
// baseline (1324.043 us; speedup 1.0000x reference)
//
#include <hip/hip_runtime.h>
#include <math.h>

#define N_NODES 100000
#define N_EDGES 3200000
#define F_NODE 4
#define F_EDGE 4
#define LD 6
#define HID 16
#define NLAYER 8
#define EPSF 1e-6f

#define NPB 64                      // nodes per bucket
#define NBK 1563                    // ceil(N_NODES/64)
#define G1 512                      // blocks for hist/scatter
#define CH (N_EDGES / G1)           // 6250 edges per block

// ---------- bf16 helpers (RNE pack, low half = first elem) ----------
__device__ __forceinline__ unsigned f2bf(float a, float b) {
    unsigned ua = __float_as_uint(a);
    ua = (ua + 0x7fffu + ((ua >> 16) & 1u)) >> 16;
    unsigned ub = __float_as_uint(b);
    ub = (ub + 0x7fffu + ((ub >> 16) & 1u)) & 0xffff0000u;
    return ua | ub;
}
__device__ __forceinline__ float bflo(unsigned u) { return __uint_as_float(u << 16); }
__device__ __forceinline__ float bfhi(unsigned u) { return __uint_as_float(u & 0xffff0000u); }

// ==================== phase 1: per-block LDS histograms (no global atomics) ====================
__global__ __launch_bounds__(256) void hist_kernel(const int* __restrict__ ei,
                                                   int* __restrict__ ghd,
                                                   int* __restrict__ ghs) {
    __shared__ int hd[NBK];
    __shared__ int hs[NBK];
    int t = threadIdx.x;
    for (int i = t; i < NBK; i += 256) { hd[i] = 0; hs[i] = 0; }
    __syncthreads();
    int beg = blockIdx.x * CH, end = beg + CH;
    for (int e = beg + t; e < end; e += 256) {
        atomicAdd(&hs[ei[e] >> 6], 1);
        atomicAdd(&hd[ei[N_EDGES + e] >> 6], 1);
    }
    __syncthreads();
    int* gd = ghd + (size_t)blockIdx.x * NBK;
    int* gs = ghs + (size_t)blockIdx.x * NBK;
    for (int i = t; i < NBK; i += 256) { gd[i] = hd[i]; gs[i] = hs[i]; }
}

// ==================== phase 2a: per-bucket scan over blocks (in-place -> prefixes) ====================
__global__ __launch_bounds__(64) void scanb_kernel(int* __restrict__ ghd, int* __restrict__ ghs,
                                                   int* __restrict__ totd, int* __restrict__ tots) {
    int b = blockIdx.x, t = threadIdx.x;
#pragma unroll
    for (int a = 0; a < 2; a++) {
        int* g = a ? ghs : ghd;
        int vals[8];
        int sum = 0;
#pragma unroll
        for (int k = 0; k < 8; k++) { vals[k] = g[(size_t)(t * 8 + k) * NBK + b]; sum += vals[k]; }
        int pre = sum;
        for (int off = 1; off < 64; off <<= 1) { int v = __shfl_up(pre, off, 64); if (t >= off) pre += v; }
        int excl = pre - sum;
        int tot = __shfl(pre, 63, 64);
#pragma unroll
        for (int k = 0; k < 8; k++) { g[(size_t)(t * 8 + k) * NBK + b] = excl; excl += vals[k]; }
        if (t == 0) (a ? tots : totd)[b] = tot;
    }
}

// ==================== phase 2b: exclusive scan of bucket totals ====================
__global__ __launch_bounds__(256) void totscan_kernel(const int* __restrict__ totd,
                                                      const int* __restrict__ tots,
                                                      int* __restrict__ based,
                                                      int* __restrict__ bases) {
    __shared__ int part[256];
    int t = threadIdx.x;
#pragma unroll
    for (int a = 0; a < 2; a++) {
        const int* tot = a ? tots : totd;
        int* base = a ? bases : based;
        int loc[7];
        int sum = 0;
#pragma unroll
        for (int k = 0; k < 7; k++) { int i = t * 7 + k; loc[k] = (i < NBK) ? tot[i] : 0; sum += loc[k]; }
        part[t] = sum;
        __syncthreads();
        for (int off = 1; off < 256; off <<= 1) {
            int v = (t >= off) ? part[t - off] : 0;
            __syncthreads();
            part[t] += v;
            __syncthreads();
        }
        int excl = part[t] - sum;
#pragma unroll
        for (int k = 0; k < 7; k++) { int i = t * 7 + k; if (i < NBK) base[i] = excl; excl += loc[k]; }
        __syncthreads();
    }
}

// ==================== phase 3: binned scatter (LDS cursors only) ====================
__global__ __launch_bounds__(256) void scatter_kernel(const int* __restrict__ ei,
                                                      const float* __restrict__ ea,
                                                      const int* __restrict__ ghd,
                                                      const int* __restrict__ ghs,
                                                      const int* __restrict__ based,
                                                      const int* __restrict__ bases,
                                                      int4* __restrict__ rec,
                                                      int* __restrict__ ebuf,
                                                      int2* __restrict__ sbuf) {
    __shared__ int curd[NBK];
    __shared__ int curs[NBK];
    int t = threadIdx.x, blk = blockIdx.x;
    const int* gd = ghd + (size_t)blk * NBK;
    const int* gs = ghs + (size_t)blk * NBK;
    for (int i = t; i < NBK; i += 256) { curd[i] = based[i] + gd[i]; curs[i] = bases[i] + gs[i]; }
    __syncthreads();
    int beg = blk * CH, end = beg + CH;
    for (int e = beg + t; e < end; e += 256) {
        int s = ei[e], d = ei[N_EDGES + e];
        float4 ev = reinterpret_cast<const float4*>(ea)[e];
        int p = atomicAdd(&curd[d >> 6], 1);
        rec[p] = make_int4(s, d, (int)f2bf(ev.x, ev.y), (int)f2bf(ev.z, ev.w));
        ebuf[p] = e;
        int q = atomicAdd(&curs[s >> 6], 1);
        sbuf[q] = make_int2(e, s);
    }
}

// ==================== layer-0 A/B tables from node attrs ====================
// A[v] = x[v]@W1[12:16] + b1 ; B[v] = x[v]@W1[16:20]   (X = 0 at layer 0)
__global__ __launch_bounds__(256) void ab_init(const float* __restrict__ x,
                                               const float* __restrict__ W1,
                                               const float* __restrict__ b1,
                                               unsigned* __restrict__ A,
                                               unsigned* __restrict__ B) {
    __shared__ float sW[8 * HID];
    __shared__ float sb[HID];
    int t = threadIdx.x;
    for (int i = t; i < 8 * HID; i += 256) sW[i] = W1[12 * HID + i];
    if (t < HID) sb[t] = b1[t];
    __syncthreads();
    int i = blockIdx.x * 256 + t;
    if (i >= N_NODES) return;
    float4 xv = reinterpret_cast<const float4*>(x)[i];
    float xf[4] = {xv.x, xv.y, xv.z, xv.w};
    float a[HID], bb[HID];
#pragma unroll
    for (int j = 0; j < HID; j++) { a[j] = sb[j]; bb[j] = 0.0f; }
#pragma unroll
    for (int r = 0; r < 4; r++) {
        float v = xf[r];
#pragma unroll
        for (int j = 0; j < HID; j++) {
            a[j]  = fmaf(v, sW[r * HID + j], a[j]);
            bb[j] = fmaf(v, sW[(4 + r) * HID + j], bb[j]);
        }
    }
    uint4* Ao = reinterpret_cast<uint4*>(A + (size_t)i * 8);
    Ao[0] = make_uint4(f2bf(a[0], a[1]), f2bf(a[2], a[3]), f2bf(a[4], a[5]), f2bf(a[6], a[7]));
    Ao[1] = make_uint4(f2bf(a[8], a[9]), f2bf(a[10], a[11]), f2bf(a[12], a[13]), f2bf(a[14], a[15]));
    uint4* Bo = reinterpret_cast<uint4*>(B + (size_t)i * 8);
    Bo[0] = make_uint4(f2bf(bb[0], bb[1]), f2bf(bb[2], bb[3]), f2bf(bb[4], bb[5]), f2bf(bb[6], bb[7]));
    Bo[1] = make_uint4(f2bf(bb[8], bb[9]), f2bf(bb[10], bb[11]), f2bf(bb[12], bb[13]), f2bf(bb[14], bb[15]));
}

// ==================== per-layer: edge MLP + LDS aggregation + node update + next A/B ====================
template <int LAST>
__global__ __launch_bounds__(256) void edge_layer(const int4* __restrict__ rec,
                                                  const unsigned* __restrict__ Ain,
                                                  const unsigned* __restrict__ Bin,
                                                  const float* __restrict__ x,
                                                  const float* __restrict__ W1l,
                                                  const float* __restrict__ W2l,
                                                  const float* __restrict__ b2l,
                                                  const float* __restrict__ W1n,
                                                  const float* __restrict__ b1n,
                                                  const float* __restrict__ Wf,
                                                  const float* __restrict__ bfp,
                                                  const int* __restrict__ based,
                                                  const int* __restrict__ totd,
                                                  unsigned* __restrict__ Aout,
                                                  unsigned* __restrict__ Bout,
                                                  float* __restrict__ Pout,
                                                  float* __restrict__ Pbuf) {
    __shared__ float sWea[4 * HID];
    __shared__ float sW2[HID * LD];
    __shared__ float sb2[LD];
    __shared__ float sW1n[20 * HID];
    __shared__ float sb1n[HID];
    __shared__ float sWf[LD];
    __shared__ float sbf;
    __shared__ float accf[LD * NPB];
    __shared__ int scnt[NPB];
    int t = threadIdx.x;
    for (int i = t; i < 4 * HID; i += 256) sWea[i] = W1l[20 * HID + i];
    for (int i = t; i < HID * LD; i += 256) sW2[i] = W2l[i];
    if (t < LD) sb2[t] = b2l[t];
    if (!LAST) {
        for (int i = t; i < 20 * HID; i += 256) sW1n[i] = W1n[i];
        if (t < HID) sb1n[t] = b1n[t];
    } else {
        if (t < LD) sWf[t] = Wf[t];
        if (t == 0) sbf = bfp[0];
    }
    for (int i = t; i < LD * NPB; i += 256) accf[i] = 0.0f;
    if (t < NPB) scnt[t] = 0;
    __syncthreads();

    int b = blockIdx.x;
    int beg = based[b], end = beg + totd[b];
    for (int p = beg + t; p < end; p += 256) {
        int4 r = rec[p];
        int s = r.x, d = r.y;
        const uint4* Ap = reinterpret_cast<const uint4*>(Ain + (size_t)s * 8);
        uint4 ax = Ap[0], ay = Ap[1];
        const uint4* Bp = reinterpret_cast<const uint4*>(Bin + (size_t)d * 8);
        uint4 bx = Bp[0], by = Bp[1];
        float h[HID];
        h[0]  = bflo(ax.x) + bflo(bx.x);  h[1]  = bfhi(ax.x) + bfhi(bx.x);
        h[2]  = bflo(ax.y) + bflo(bx.y);  h[3]  = bfhi(ax.y) + bfhi(bx.y);
        h[4]  = bflo(ax.z) + bflo(bx.z);  h[5]  = bfhi(ax.z) + bfhi(bx.z);
        h[6]  = bflo(ax.w) + bflo(bx.w);  h[7]  = bfhi(ax.w) + bfhi(bx.w);
        h[8]  = bflo(ay.x) + bflo(by.x);  h[9]  = bfhi(ay.x) + bfhi(by.x);
        h[10] = bflo(ay.y) + bflo(by.y);  h[11] = bfhi(ay.y) + bfhi(by.y);
        h[12] = bflo(ay.z) + bflo(by.z);  h[13] = bfhi(ay.z) + bfhi(by.z);
        h[14] = bflo(ay.w) + bflo(by.w);  h[15] = bfhi(ay.w) + bfhi(by.w);
        float ef[4] = {bflo((unsigned)r.z), bfhi((unsigned)r.z),
                       bflo((unsigned)r.w), bfhi((unsigned)r.w)};
#pragma unroll
        for (int rr = 0; rr < 4; rr++) {
            float v = ef[rr];
#pragma unroll
            for (int j = 0; j < HID; j++) h[j] = fmaf(v, sWea[rr * HID + j], h[j]);
        }
#pragma unroll
        for (int j = 0; j < HID; j++) h[j] = fmaxf(h[j], 0.0f);
        float m[LD];
#pragma unroll
        for (int o = 0; o < LD; o++) m[o] = sb2[o];
#pragma unroll
        for (int j = 0; j < HID; j++) {
            float hj = h[j];
#pragma unroll
            for (int o = 0; o < LD; o++) m[o] = fmaf(hj, sW2[j * LD + o], m[o]);
        }
        int dl = d & (NPB - 1);
#pragma unroll
        for (int o = 0; o < LD; o++) atomicAdd(&accf[o * NPB + dl], m[o]);
        atomicAdd(&scnt[dl], 1);
    }
    __syncthreads();

    if (t < NPB) {
        int gid = (b << 6) + t;
        if (gid < N_NODES) {
            float inv = 1.0f / fmaxf((float)scnt[t], 1.0f);
            float Xv[LD];
#pragma unroll
            for (int o = 0; o < LD; o++) Xv[o] = fmaxf(accf[o * NPB + t] * inv, 0.0f);
            if (LAST) {
                float acc = sbf;
#pragma unroll
                for (int o = 0; o < LD; o++) acc = fmaf(Xv[o], sWf[o], acc);
                float P = fmaxf(acc, 0.0f);
                Pout[gid] = P;
                float fx = x[gid * F_NODE + 3];
                Pbuf[gid] = (fx != 0.0f) ? fx : P;
            } else {
                float4 xv = reinterpret_cast<const float4*>(x)[gid];
                float xf[4] = {xv.x, xv.y, xv.z, xv.w};
                float a[HID], bb[HID];
#pragma unroll
                for (int j = 0; j < HID; j++) { a[j] = sb1n[j]; bb[j] = 0.0f; }
#pragma unroll
                for (int rr = 0; rr < LD; rr++) {
                    float v = Xv[rr];
#pragma unroll
                    for (int j = 0; j < HID; j++) {
                        a[j]  = fmaf(v, sW1n[rr * HID + j], a[j]);
                        bb[j] = fmaf(v, sW1n[(LD + rr) * HID + j], bb[j]);
                    }
                }
#pragma unroll
                for (int rr = 0; rr < 4; rr++) {
                    float v = xf[rr];
#pragma unroll
                    for (int j = 0; j < HID; j++) {
                        a[j]  = fmaf(v, sW1n[(12 + rr) * HID + j], a[j]);
                        bb[j] = fmaf(v, sW1n[(16 + rr) * HID + j], bb[j]);
                    }
                }
                uint4* Ao = reinterpret_cast<uint4*>(Aout + (size_t)gid * 8);
                Ao[0] = make_uint4(f2bf(a[0], a[1]), f2bf(a[2], a[3]), f2bf(a[4], a[5]), f2bf(a[6], a[7]));
                Ao[1] = make_uint4(f2bf(a[8], a[9]), f2bf(a[10], a[11]), f2bf(a[12], a[13]), f2bf(a[14], a[15]));
                uint4* Bo = reinterpret_cast<uint4*>(Bout + (size_t)gid * 8);
                Bo[0] = make_uint4(f2bf(bb[0], bb[1]), f2bf(bb[2], bb[3]), f2bf(bb[4], bb[5]), f2bf(bb[6], bb[7]));
                Bo[1] = make_uint4(f2bf(bb[8], bb[9]), f2bf(bb[10], bb[11]), f2bf(bb[12], bb[13]), f2bf(bb[14], bb[15]));
            }
        }
    }
}

// ==================== flows (original edge order, fp32 inputs, no atomics) ====================
__global__ __launch_bounds__(256) void flows_noatomic(const int* __restrict__ ei,
                                                      const float* __restrict__ ea,
                                                      const float* __restrict__ Pbuf,
                                                      float* __restrict__ flows_out) {
    int e = blockIdx.x * 256 + threadIdx.x;
    if (e >= N_EDGES) return;
    int s = ei[e];
    int d = ei[N_EDGES + e];
    float ps = Pbuf[s], pd = Pbuf[d];
    float dp2 = ps * ps - pd * pd;
    float k = ea[(size_t)e * F_EDGE];
    float sg = (dp2 > 0.0f) ? 1.0f : ((dp2 < 0.0f) ? -1.0f : 0.0f);
    flows_out[e] = sg * sqrtf(fabsf(dp2) / k + EPSF);
}

// ==================== balance: in-flow per bucket (LDS), bal = acc + inj ====================
__global__ __launch_bounds__(256) void balance_in(const int4* __restrict__ rec,
                                                  const int* __restrict__ ebuf,
                                                  const float* __restrict__ flows,
                                                  const float* __restrict__ x,
                                                  const int* __restrict__ based,
                                                  const int* __restrict__ totd,
                                                  float* __restrict__ bal) {
    __shared__ float acc[NPB];
    int t = threadIdx.x;
    if (t < NPB) acc[t] = 0.0f;
    __syncthreads();
    int b = blockIdx.x;
    int beg = based[b], end = beg + totd[b];
    for (int p = beg + t; p < end; p += 256) {
        int d = rec[p].y;
        int e = ebuf[p];
        atomicAdd(&acc[d & (NPB - 1)], flows[e]);
    }
    __syncthreads();
    if (t < NPB) {
        int gid = (b << 6) + t;
        if (gid < N_NODES) bal[gid] = acc[t] + x[gid * F_NODE + 0];
    }
}

// ==================== balance: out-flow per src-bucket + imbalance partial ====================
__global__ __launch_bounds__(256) void balance_out(const int2* __restrict__ sbuf,
                                                   const float* __restrict__ flows,
                                                   const int* __restrict__ bases,
                                                   const int* __restrict__ tots,
                                                   const float* __restrict__ bal,
                                                   float* __restrict__ imb2) {
    __shared__ float acc[NPB];
    int t = threadIdx.x;
    if (t < NPB) acc[t] = 0.0f;
    __syncthreads();
    int b = blockIdx.x;
    int beg = bases[b], end = beg + tots[b];
    for (int q = beg + t; q < end; q += 256) {
        int2 r = sbuf[q];
        atomicAdd(&acc[r.y & (NPB - 1)], flows[r.x]);
    }
    __syncthreads();
    if (t < NPB) {  // all in wave 0
        float v = 0.0f;
        int gid = (b << 6) + t;
        if (gid < N_NODES) {
            float bv = bal[gid] - acc[t];
            v = bv * bv;
        }
#pragma unroll
        for (int off = 32; off > 0; off >>= 1) v += __shfl_down(v, off, 64);
        if (t == 0) atomicAdd(imb2, v);
    }
}

__global__ void fin_kernel(const float* __restrict__ imb2, float* __restrict__ out) {
    out[0] = sqrtf(imb2[0]);
}

// ==================== launch ====================
extern "C" void kernel_launch(void* const* d_in, const int* in_sizes, int n_in,
                              void* d_out, int out_size, void* d_ws, size_t ws_size,
                              hipStream_t stream) {
    const float* x   = (const float*)d_in[0];
    const float* ea  = (const float*)d_in[1];
    const int*   ei  = (const int*)d_in[2];
    const float* W1  = (const float*)d_in[3];
    const float* b1  = (const float*)d_in[4];
    const float* W2  = (const float*)d_in[5];
    const float* b2  = (const float*)d_in[6];
    const float* Wf  = (const float*)d_in[7];
    const float* bf_ = (const float*)d_in[8];
    float* out = (float*)d_out;

    const size_t N = N_NODES, E = N_EDGES;

    // ---- workspace layout (4B elements, 16B-aligned chunks), ~111 MB ----
    size_t o = 0;
    auto alloc = [&](size_t n) { size_t r = o; o += (n + 3) & ~(size_t)3; return r; };
    size_t o_rec   = alloc(4 * E);
    size_t o_ebuf  = alloc(E);
    size_t o_sbuf  = alloc(2 * E);
    size_t o_ghd   = alloc((size_t)G1 * NBK);
    size_t o_ghs   = alloc((size_t)G1 * NBK);
    size_t o_totd  = alloc(NBK);
    size_t o_tots  = alloc(NBK);
    size_t o_based = alloc(NBK);
    size_t o_bases = alloc(NBK);
    size_t o_A0    = alloc(8 * N);
    size_t o_B0    = alloc(8 * N);
    size_t o_A1    = alloc(8 * N);
    size_t o_B1    = alloc(8 * N);
    size_t o_Pbuf  = alloc(N);
    size_t o_bal   = alloc(N);
    size_t o_imb2  = alloc(16);
    (void)o;

    int* wsi = (int*)d_ws;
    int4*     rec   = (int4*)(wsi + o_rec);
    int*      ebuf  = wsi + o_ebuf;
    int2*     sbuf  = (int2*)(wsi + o_sbuf);
    int*      ghd   = wsi + o_ghd;
    int*      ghs   = wsi + o_ghs;
    int*      totd  = wsi + o_totd;
    int*      tots  = wsi + o_tots;
    int*      based = wsi + o_based;
    int*      bases = wsi + o_bases;
    unsigned* A0    = (unsigned*)(wsi + o_A0);
    unsigned* B0    = (unsigned*)(wsi + o_B0);
    unsigned* A1    = (unsigned*)(wsi + o_A1);
    unsigned* B1    = (unsigned*)(wsi + o_B1);
    float*    Pbuf  = (float*)(wsi + o_Pbuf);
    float*    bal   = (float*)(wsi + o_bal);
    float*    imb2  = (float*)(wsi + o_imb2);

    const int NB = (N_NODES + 255) / 256;   // 391
    const int EB = (N_EDGES + 255) / 256;   // 12500

    hipMemsetAsync(imb2, 0, sizeof(float), stream);

    hist_kernel<<<G1, 256, 0, stream>>>(ei, ghd, ghs);
    scanb_kernel<<<NBK, 64, 0, stream>>>(ghd, ghs, totd, tots);
    totscan_kernel<<<1, 256, 0, stream>>>(totd, tots, based, bases);
    scatter_kernel<<<G1, 256, 0, stream>>>(ei, ea, ghd, ghs, based, bases,
                                           rec, ebuf, sbuf);

    ab_init<<<NB, 256, 0, stream>>>(x, W1, b1, A0, B0);

    for (int l = 0; l < NLAYER; l++) {
        const unsigned* Ain = (l & 1) ? A1 : A0;
        const unsigned* Bin = (l & 1) ? B1 : B0;
        unsigned* Aout = (l & 1) ? A0 : A1;
        unsigned* Bout = (l & 1) ? B0 : B1;
        const float* W1l = W1 + (size_t)l * 24 * HID;
        const float* W2l = W2 + (size_t)l * HID * LD;
        const float* b2l = b2 + (size_t)l * LD;
        if (l < NLAYER - 1) {
            edge_layer<0><<<NBK, 256, 0, stream>>>(rec, Ain, Bin, x, W1l, W2l, b2l,
                                                   W1 + (size_t)(l + 1) * 24 * HID,
                                                   b1 + (size_t)(l + 1) * HID,
                                                   Wf, bf_, based, totd,
                                                   Aout, Bout, out, Pbuf);
        } else {
            edge_layer<1><<<NBK, 256, 0, stream>>>(rec, Ain, Bin, x, W1l, W2l, b2l,
                                                   W1, b1, Wf, bf_, based, totd,
                                                   Aout, Bout, out, Pbuf);
        }
    }

    flows_noatomic<<<EB, 256, 0, stream>>>(ei, ea, Pbuf, out + N);
    balance_in<<<NBK, 256, 0, stream>>>(rec, ebuf, out + N, x, based, totd, bal);
    balance_out<<<NBK, 256, 0, stream>>>(sbuf, out + N, bases, tots, bal, imb2);
    fin_kernel<<<1, 1, 0, stream>>>(imb2, out + (size_t)N + E);
}